// Round 12
// baseline (44.620 us; speedup 1.0000x reference)
//
#include <hip/hip_runtime.h>
#include <math.h>

#define LAMBDA_DECAY 0.01f
#define ALPHA 0.95f
#define LN_EPS 1e-5f

// Geometry (reference: M=8192, D=4096).
#define NB 512       // K1 blocks
#define RPB 16       // rows per block = M/NB
#define WPB 8        // waves per block (512 threads); wave owns D/8 = 512 cols
#define TB 32        // tail blocks; each owns D/TB = 128 columns

typedef float v4f __attribute__((ext_vector_type(4)));

static __device__ __forceinline__ float wave_sum_all(float v) {
#pragma unroll
    for (int o = 32; o > 0; o >>= 1) v += __shfl_xor(v, o);
    return v;
}

static __device__ float block_sum(float v, float* sh, int nwaves) {
    int lane = threadIdx.x & 63;
    int w = threadIdx.x >> 6;
    v = wave_sum_all(v);
    if (lane == 0) sh[w] = v;
    __syncthreads();
    float r = 0.0f;
    for (int i = 0; i < nwaves; ++i) r += sh[i];
    __syncthreads();
    return r;
}

// K1: single pass over states — EXACT R6 hot loop (best so far, 37.2us).
// Only addition: block 0 zeroes attn_raw + counter for the fused tail
// (kernel-boundary ordering makes this visible to the tail kernel; handles
// the harness's one-time 0xAA ws poison and leaves state clean per replay).
__global__ __launch_bounds__(512) void fused_kernel(
    const float* __restrict__ states, const float* __restrict__ cur,
    const float* __restrict__ weights, const float* __restrict__ ts,
    const float* __restrict__ t_new,
    float* __restrict__ partial, float* __restrict__ partE, float* __restrict__ partS,
    float* __restrict__ attn_raw, unsigned* __restrict__ counter,
    int M, int D, float scale)
{
    __shared__ float shp[2][WPB];

    const int wid = threadIdx.x >> 6;
    const int lane = threadIdx.x & 63;
    const int r0 = blockIdx.x * RPB;
    const int f4base = wid * 128 + lane;     // float4 index of lane's first elem
    const int rstride = D >> 2;              // row stride in float4 (1024)

    if (blockIdx.x == 0) {
        for (int d = threadIdx.x; d < D; d += 512) attn_raw[d] = 0.0f;
        if (threadIdx.x == 0) *counter = 0u;
    }

    const float tn = t_new[0];

    const v4f* c4 = (const v4f*)cur;
    const v4f curp0 = c4[f4base];
    const v4f curp1 = c4[f4base + 64];

    v4f acc0 = (v4f)(0.0f), acc1 = (v4f)(0.0f);
    float E = 0.0f, S = 0.0f;

    const v4f* sp = (const v4f*)states;

    v4f rv[2][2];
    rv[0][0] = sp[(size_t)r0 * rstride + f4base];
    rv[0][1] = sp[(size_t)r0 * rstride + f4base + 64];

#pragma unroll
    for (int r = 0; r < RPB; ++r) {
        const int row = r0 + r;
        const int cb = r & 1;        // compile-time after full unroll
        const int nb = cb ^ 1;

        // Prefetch next row.
        if (r + 1 < RPB) {
            rv[nb][0] = sp[(size_t)(row + 1) * rstride + f4base];
            rv[nb][1] = sp[(size_t)(row + 1) * rstride + f4base + 64];
        }

        const v4f a0 = rv[cb][0], a1 = rv[cb][1];

        float d0 = 0.0f, d1 = 0.0f;
        d0 = fmaf(a0[0], curp0[0], d0); d1 = fmaf(a1[0], curp1[0], d1);
        d0 = fmaf(a0[1], curp0[1], d0); d1 = fmaf(a1[1], curp1[1], d1);
        d0 = fmaf(a0[2], curp0[2], d0); d1 = fmaf(a1[2], curp1[2], d1);
        d0 = fmaf(a0[3], curp0[3], d0); d1 = fmaf(a1[3], curp1[3], d1);
        float pd = wave_sum_all(d0 + d1);

        if (lane == 0) shp[cb][wid] = pd;
        __syncthreads();

        float s = 0.0f;
#pragma unroll
        for (int w = 0; w < WPB; ++w) s += shp[cb][w];   // same addr: broadcast
        s *= scale;

        const float e = expf(s);
        const float wgt = weights[row] * expf(-LAMBDA_DECAY * fabsf(tn - ts[row]));
        const float p = e * wgt;
        E += e; S += p;                                   // uniform across threads

        acc0 += p * a0;
        acc1 += p * a1;
    }

    v4f* pb = (v4f*)(partial + (size_t)blockIdx.x * D);
    pb[f4base] = acc0;
    pb[f4base + 64] = acc1;
    if (threadIdx.x == 0) {
        partE[blockIdx.x] = E;
        partS[blockIdx.x] = S;
    }
}

// Fused tail (replaces K2 + K3, removing one dispatch gap).
// 32 blocks x 256 threads. Block b owns cols [b*128, b*128+128); threads
// 0-127 sum partial rows 0-255 for their col, threads 128-255 rows 256-511;
// halves combined in LDS; ONE atomicAdd per column into attn_raw (zeroed in
// K1 -> deterministic single-add value, coherent at device scope).
// Then threadfence + counter; the LAST block acquires, reduces partE/partS,
// blends with cur, LayerNorms, writes out, and resets the counter.
__global__ __launch_bounds__(256) void tail_kernel(
    const float* __restrict__ partial, const float* __restrict__ partE,
    const float* __restrict__ partS, const float* __restrict__ cur,
    float* __restrict__ attn_raw, unsigned* __restrict__ counter,
    float* __restrict__ out, int D)
{
    __shared__ float shc[128];
    __shared__ float sh16[16];
    __shared__ unsigned sdone;

    const int cid = threadIdx.x & 127;
    const int half = threadIdx.x >> 7;
    const int col = blockIdx.x * 128 + cid;

    {
        const int b0 = half * (NB / 2);
        float a0 = 0.0f, a1 = 0.0f, a2 = 0.0f, a3 = 0.0f;
        for (int b = 0; b < NB / 2; b += 4) {
            a0 += partial[(size_t)(b0 + b) * D + col];
            a1 += partial[(size_t)(b0 + b + 1) * D + col];
            a2 += partial[(size_t)(b0 + b + 2) * D + col];
            a3 += partial[(size_t)(b0 + b + 3) * D + col];
        }
        const float a = (a0 + a1) + (a2 + a3);
        if (half) shc[cid] = a;
        __syncthreads();
        if (!half) atomicAdd(&attn_raw[col], a + shc[cid]);
    }

    __threadfence();                      // release our attn_raw adds
    __syncthreads();                      // all lanes' atomics issued & fenced
    if (threadIdx.x == 0) sdone = atomicAdd(counter, 1u);
    __syncthreads();
    if (sdone != TB - 1) return;          // not the last block

    // ---- last block: finalize ----
    if (threadIdx.x == 0) *counter = 0u;  // clean for next replay
    __threadfence();                      // acquire: invalidate local caches

    float E = 0.0f, S = 0.0f;
    for (int i = threadIdx.x; i < NB; i += 256) { E += partE[i]; S += partS[i]; }
    E = block_sum(E, sh16, 4);
    S = block_sum(S, sh16, 4);
    const float inv = 1.0f / (S + 1e-9f * E);

    float v[16];
    float s = 0.0f, s2 = 0.0f;
#pragma unroll
    for (int k = 0; k < 16; ++k) {
        const int c = threadIdx.x + k * 256;
        const float nv = ALPHA * cur[c] + (1.0f - ALPHA) * (attn_raw[c] * inv);
        v[k] = nv;
        s += nv; s2 += nv * nv;
    }
    s = block_sum(s, sh16, 4);
    s2 = block_sum(s2, sh16, 4);
    const float mean = s / (float)D;
    const float var = s2 / (float)D - mean * mean;
    const float rstd = 1.0f / sqrtf(var + LN_EPS);
#pragma unroll
    for (int k = 0; k < 16; ++k)
        out[threadIdx.x + k * 256] = (v[k] - mean) * rstd;
}

extern "C" void kernel_launch(void* const* d_in, const int* in_sizes, int n_in,
                              void* d_out, int out_size, void* d_ws, size_t ws_size,
                              hipStream_t stream) {
    const float* states     = (const float*)d_in[0];
    const float* weights    = (const float*)d_in[1];
    const float* timestamps = (const float*)d_in[2];
    const float* current    = (const float*)d_in[3];
    // d_in[4] = sensed_state: not used in the output math.
    const float* t_new      = (const float*)d_in[5];
    float* out = (float*)d_out;

    const int M = in_sizes[1];   // 8192
    const int D = in_sizes[3];   // 4096

    float* ws        = (float*)d_ws;
    float* partial   = ws;                              // [NB * D] (8 MiB)
    float* partE     = partial + (size_t)NB * D;        // [NB]
    float* partS     = partE + NB;                      // [NB]
    float* attn_raw  = partS + NB;                      // [D]
    unsigned* counter = (unsigned*)(attn_raw + D);      // [1]

    const float scale = 1.0f / sqrtf((float)D);

    fused_kernel<<<NB, 512, 0, stream>>>(
        states, current, weights, timestamps, t_new,
        partial, partE, partS, attn_raw, counter, M, D, scale);

    tail_kernel<<<TB, 256, 0, stream>>>(
        partial, partE, partS, current, attn_raw, counter, out, D);
}

// Round 13
// 37.423 us; speedup vs baseline: 1.1923x; 1.1923x over previous
//
#include <hip/hip_runtime.h>
#include <math.h>

#define LAMBDA_DECAY 0.01f
#define ALPHA 0.95f
#define LN_EPS 1e-5f

// Geometry (reference: M=8192, D=4096).
#define NB 512       // K1 blocks
#define RPB 16       // rows per block = M/NB
#define WPB 8        // waves per block (512 threads); wave owns D/8 = 512 cols
#define G2 64        // partials per K2 block
#define NP2 8        // NB/G2

typedef float v4f __attribute__((ext_vector_type(4)));

static __device__ __forceinline__ float wave_sum_all(float v) {
#pragma unroll
    for (int o = 32; o > 0; o >>= 1) v += __shfl_xor(v, o);
    return v;
}

static __device__ float block_sum(float v, float* sh, int nwaves) {
    int lane = threadIdx.x & 63;
    int w = threadIdx.x >> 6;
    v = wave_sum_all(v);
    if (lane == 0) sh[w] = v;
    __syncthreads();
    float r = 0.0f;
    for (int i = 0; i < nwaves; ++i) r += sh[i];
    __syncthreads();
    return r;
}

// K1: single pass over states (best structure found — R6, 37.2us).
// 8 waves/block; wave owns a 512-float D-slice (2 float4/lane). Per row:
// prefetch next row's slice, partial dot, shuffle-reduce, exchange 8
// partials via double-buffered LDS with __syncthreads.
// Falsified alternatives (kept for the record): deeper row buffers spill
// (R7); lgkmcnt-only barrier regresses (R8); atomic tails regress (R9/R12);
// barrier batching null (R10); more blocks/CU trades tail traffic (R11).
__global__ __launch_bounds__(512) void fused_kernel(
    const float* __restrict__ states, const float* __restrict__ cur,
    const float* __restrict__ weights, const float* __restrict__ ts,
    const float* __restrict__ t_new,
    float* __restrict__ partial, float* __restrict__ partE, float* __restrict__ partS,
    int M, int D, float scale)
{
    __shared__ float shp[2][WPB];

    const int wid = threadIdx.x >> 6;
    const int lane = threadIdx.x & 63;
    const int r0 = blockIdx.x * RPB;
    const int f4base = wid * 128 + lane;     // float4 index of lane's first elem
    const int rstride = D >> 2;              // row stride in float4 (1024)

    const float tn = t_new[0];

    const v4f* c4 = (const v4f*)cur;
    const v4f curp0 = c4[f4base];
    const v4f curp1 = c4[f4base + 64];

    v4f acc0 = (v4f)(0.0f), acc1 = (v4f)(0.0f);
    float E = 0.0f, S = 0.0f;

    const v4f* sp = (const v4f*)states;

    v4f rv[2][2];
    rv[0][0] = sp[(size_t)r0 * rstride + f4base];
    rv[0][1] = sp[(size_t)r0 * rstride + f4base + 64];

#pragma unroll
    for (int r = 0; r < RPB; ++r) {
        const int row = r0 + r;
        const int cb = r & 1;        // compile-time after full unroll
        const int nb = cb ^ 1;

        // Prefetch next row.
        if (r + 1 < RPB) {
            rv[nb][0] = sp[(size_t)(row + 1) * rstride + f4base];
            rv[nb][1] = sp[(size_t)(row + 1) * rstride + f4base + 64];
        }

        const v4f a0 = rv[cb][0], a1 = rv[cb][1];

        float d0 = 0.0f, d1 = 0.0f;
        d0 = fmaf(a0[0], curp0[0], d0); d1 = fmaf(a1[0], curp1[0], d1);
        d0 = fmaf(a0[1], curp0[1], d0); d1 = fmaf(a1[1], curp1[1], d1);
        d0 = fmaf(a0[2], curp0[2], d0); d1 = fmaf(a1[2], curp1[2], d1);
        d0 = fmaf(a0[3], curp0[3], d0); d1 = fmaf(a1[3], curp1[3], d1);
        float pd = wave_sum_all(d0 + d1);

        if (lane == 0) shp[cb][wid] = pd;
        __syncthreads();

        float s = 0.0f;
#pragma unroll
        for (int w = 0; w < WPB; ++w) s += shp[cb][w];   // same addr: broadcast
        s *= scale;

        const float e = expf(s);
        const float wgt = weights[row] * expf(-LAMBDA_DECAY * fabsf(tn - ts[row]));
        const float p = e * wgt;
        E += e; S += p;                                   // uniform across threads

        acc0 += p * a0;
        acc1 += p * a1;
    }

    v4f* pb = (v4f*)(partial + (size_t)blockIdx.x * D);
    pb[f4base] = acc0;
    pb[f4base + 64] = acc1;
    if (threadIdx.x == 0) {
        partE[blockIdx.x] = E;
        partS[blockIdx.x] = S;
    }
}

// K2: tree-reduce partials NB -> NP2 per column. grid=(D/256, NP2).
__global__ __launch_bounds__(256) void reduce_kernel(
    const float* __restrict__ partial, float* __restrict__ partial2, int D)
{
    const int col = blockIdx.x * 256 + threadIdx.x;
    const int b0 = blockIdx.y * G2;
    float a0 = 0.0f, a1 = 0.0f, a2 = 0.0f, a3 = 0.0f;
    for (int b = 0; b < G2; b += 4) {
        a0 += partial[(size_t)(b0 + b) * D + col];
        a1 += partial[(size_t)(b0 + b + 1) * D + col];
        a2 += partial[(size_t)(b0 + b + 2) * D + col];
        a3 += partial[(size_t)(b0 + b + 3) * D + col];
    }
    partial2[(size_t)blockIdx.y * D + col] = (a0 + a1) + (a2 + a3);
}

// K3: final NP2-way column sum + E/S reduce -> inv; blend; LayerNorm. 1 block.
__global__ __launch_bounds__(1024) void finalize_kernel(
    const float* __restrict__ partial2, const float* __restrict__ partE,
    const float* __restrict__ partS, const float* __restrict__ cur,
    float* __restrict__ out, int D)
{
    __shared__ float sh[16];
    const int tid = threadIdx.x;

    float E = 0.0f, S = 0.0f;
    for (int i = tid; i < NB; i += 1024) { E += partE[i]; S += partS[i]; }
    E = block_sum(E, sh, 16);
    S = block_sum(S, sh, 16);
    const float inv = 1.0f / (S + 1e-9f * E);

    float v[4];
    float s = 0.0f, s2 = 0.0f;
#pragma unroll
    for (int k = 0; k < 4; ++k) {
        const int c = tid + k * 1024;
        float a = 0.0f;
#pragma unroll
        for (int y = 0; y < NP2; ++y) a += partial2[y * D + c];
        const float nv = ALPHA * cur[c] + (1.0f - ALPHA) * (a * inv);
        v[k] = nv;
        s += nv; s2 += nv * nv;
    }
    s = block_sum(s, sh, 16);
    s2 = block_sum(s2, sh, 16);
    const float mean = s / (float)D;
    const float var = s2 / (float)D - mean * mean;
    const float rstd = 1.0f / sqrtf(var + LN_EPS);
#pragma unroll
    for (int k = 0; k < 4; ++k)
        out[tid + k * 1024] = (v[k] - mean) * rstd;
}

extern "C" void kernel_launch(void* const* d_in, const int* in_sizes, int n_in,
                              void* d_out, int out_size, void* d_ws, size_t ws_size,
                              hipStream_t stream) {
    const float* states     = (const float*)d_in[0];
    const float* weights    = (const float*)d_in[1];
    const float* timestamps = (const float*)d_in[2];
    const float* current    = (const float*)d_in[3];
    // d_in[4] = sensed_state: not used in the output math.
    const float* t_new      = (const float*)d_in[5];
    float* out = (float*)d_out;

    const int M = in_sizes[1];   // 8192
    const int D = in_sizes[3];   // 4096

    float* ws       = (float*)d_ws;
    float* partial  = ws;                              // [NB * D] (8 MiB)
    float* partial2 = partial + (size_t)NB * D;        // [NP2 * D]
    float* partE    = partial2 + (size_t)NP2 * D;      // [NB]
    float* partS    = partE + NB;                      // [NB]

    const float scale = 1.0f / sqrtf((float)D);

    fused_kernel<<<NB, 512, 0, stream>>>(
        states, current, weights, timestamps, t_new,
        partial, partE, partS, M, D, scale);

    {
        dim3 grid(D / 256, NP2);   // (16, 8)
        reduce_kernel<<<grid, 256, 0, stream>>>(partial, partial2, D);
    }

    finalize_kernel<<<1, 1024, 0, stream>>>(partial2, partE, partS, current, out, D);
}

// Round 14
// 37.339 us; speedup vs baseline: 1.1950x; 1.0023x over previous
//
#include <hip/hip_runtime.h>
#include <math.h>

#define LAMBDA_DECAY 0.01f
#define ALPHA 0.95f
#define LN_EPS 1e-5f

// Geometry (reference: M=8192, D=4096).
#define NB 512       // K1 blocks
#define RPB 16       // rows per block = M/NB
#define WPB 8        // waves per block (512 threads); wave owns D/8 = 512 cols
#define G2 64        // partials per K2 block
#define NP2 8        // NB/G2

typedef float v4f __attribute__((ext_vector_type(4)));

static __device__ __forceinline__ float wave_sum_all(float v) {
#pragma unroll
    for (int o = 32; o > 0; o >>= 1) v += __shfl_xor(v, o);
    return v;
}

static __device__ float block_sum(float v, float* sh, int nwaves) {
    int lane = threadIdx.x & 63;
    int w = threadIdx.x >> 6;
    v = wave_sum_all(v);
    if (lane == 0) sh[w] = v;
    __syncthreads();
    float r = 0.0f;
    for (int i = 0; i < nwaves; ++i) r += sh[i];
    __syncthreads();
    return r;
}

// K1: single pass over states — R6 structure with ONE change: prefetch is
// issued AFTER the barrier, into a THIRD row buffer.
// Why: __syncthreads drains vmcnt(0). In R6 the r+1 prefetch was issued
// ~150cy before the row-r barrier, so every barrier paid a near-full stream
// wait and the post-barrier work (broadcast ds_reads + exp + acc, ~300cy)
// ran with the memory pipe EMPTY. R10 (batching, issue still pre-barrier)
// was null — consistent: idle-per-row unchanged. Here the barrier drains
// row r+1 (issued one full iteration earlier -> cheap), then row r+2 issues
// immediately and streams UNDER the post-work. 3 buffers: at iter r,
// (r+2)%3 was freed at iter r-1; dot inputs are copied to a0/a1 regs.
__global__ __launch_bounds__(512) void fused_kernel(
    const float* __restrict__ states, const float* __restrict__ cur,
    const float* __restrict__ weights, const float* __restrict__ ts,
    const float* __restrict__ t_new,
    float* __restrict__ partial, float* __restrict__ partE, float* __restrict__ partS,
    int M, int D, float scale)
{
    __shared__ float shp[2][WPB];

    const int wid = threadIdx.x >> 6;
    const int lane = threadIdx.x & 63;
    const int r0 = blockIdx.x * RPB;
    const int f4base = wid * 128 + lane;     // float4 index of lane's first elem
    const int rstride = D >> 2;              // row stride in float4 (1024)

    const float tn = t_new[0];

    const v4f* c4 = (const v4f*)cur;
    const v4f curp0 = c4[f4base];
    const v4f curp1 = c4[f4base + 64];

    v4f acc0 = (v4f)(0.0f), acc1 = (v4f)(0.0f);
    float E = 0.0f, S = 0.0f;

    const v4f* sp = (const v4f*)states;

    v4f rv[3][2];
    rv[0][0] = sp[(size_t)(r0 + 0) * rstride + f4base];
    rv[0][1] = sp[(size_t)(r0 + 0) * rstride + f4base + 64];
    rv[1][0] = sp[(size_t)(r0 + 1) * rstride + f4base];
    rv[1][1] = sp[(size_t)(r0 + 1) * rstride + f4base + 64];

#pragma unroll
    for (int r = 0; r < RPB; ++r) {
        const int row = r0 + r;
        const int cb = r % 3;        // compile-time after full unroll
        const int nxt = (r + 2) % 3; // freed at iter r-1

        const v4f a0 = rv[cb][0], a1 = rv[cb][1];   // waits vmcnt for row r only

        float d0 = 0.0f, d1 = 0.0f;
        d0 = fmaf(a0[0], curp0[0], d0); d1 = fmaf(a1[0], curp1[0], d1);
        d0 = fmaf(a0[1], curp0[1], d0); d1 = fmaf(a1[1], curp1[1], d1);
        d0 = fmaf(a0[2], curp0[2], d0); d1 = fmaf(a1[2], curp1[2], d1);
        d0 = fmaf(a0[3], curp0[3], d0); d1 = fmaf(a1[3], curp1[3], d1);
        float pd = wave_sum_all(d0 + d1);

        if (lane == 0) shp[r & 1][wid] = pd;
        __syncthreads();             // drains row r+1 (issued a full iter ago)

        // Issue row r+2 NOW: streams under the post-barrier work below.
        if (r + 2 < RPB) {
            rv[nxt][0] = sp[(size_t)(row + 2) * rstride + f4base];
            rv[nxt][1] = sp[(size_t)(row + 2) * rstride + f4base + 64];
        }

        float s = 0.0f;
#pragma unroll
        for (int w = 0; w < WPB; ++w) s += shp[r & 1][w];  // same addr: broadcast
        s *= scale;

        const float e = expf(s);
        const float wgt = weights[row] * expf(-LAMBDA_DECAY * fabsf(tn - ts[row]));
        const float p = e * wgt;
        E += e; S += p;                                    // uniform across threads

        acc0 += p * a0;
        acc1 += p * a1;
    }

    v4f* pb = (v4f*)(partial + (size_t)blockIdx.x * D);
    pb[f4base] = acc0;
    pb[f4base + 64] = acc1;
    if (threadIdx.x == 0) {
        partE[blockIdx.x] = E;
        partS[blockIdx.x] = S;
    }
}

// K2: tree-reduce partials NB -> NP2 per column. grid=(D/256, NP2).
__global__ __launch_bounds__(256) void reduce_kernel(
    const float* __restrict__ partial, float* __restrict__ partial2, int D)
{
    const int col = blockIdx.x * 256 + threadIdx.x;
    const int b0 = blockIdx.y * G2;
    float a0 = 0.0f, a1 = 0.0f, a2 = 0.0f, a3 = 0.0f;
    for (int b = 0; b < G2; b += 4) {
        a0 += partial[(size_t)(b0 + b) * D + col];
        a1 += partial[(size_t)(b0 + b + 1) * D + col];
        a2 += partial[(size_t)(b0 + b + 2) * D + col];
        a3 += partial[(size_t)(b0 + b + 3) * D + col];
    }
    partial2[(size_t)blockIdx.y * D + col] = (a0 + a1) + (a2 + a3);
}

// K3: final NP2-way column sum + E/S reduce -> inv; blend; LayerNorm. 1 block.
__global__ __launch_bounds__(1024) void finalize_kernel(
    const float* __restrict__ partial2, const float* __restrict__ partE,
    const float* __restrict__ partS, const float* __restrict__ cur,
    float* __restrict__ out, int D)
{
    __shared__ float sh[16];
    const int tid = threadIdx.x;

    float E = 0.0f, S = 0.0f;
    for (int i = tid; i < NB; i += 1024) { E += partE[i]; S += partS[i]; }
    E = block_sum(E, sh, 16);
    S = block_sum(S, sh, 16);
    const float inv = 1.0f / (S + 1e-9f * E);

    float v[4];
    float s = 0.0f, s2 = 0.0f;
#pragma unroll
    for (int k = 0; k < 4; ++k) {
        const int c = tid + k * 1024;
        float a = 0.0f;
#pragma unroll
        for (int y = 0; y < NP2; ++y) a += partial2[y * D + c];
        const float nv = ALPHA * cur[c] + (1.0f - ALPHA) * (a * inv);
        v[k] = nv;
        s += nv; s2 += nv * nv;
    }
    s = block_sum(s, sh, 16);
    s2 = block_sum(s2, sh, 16);
    const float mean = s / (float)D;
    const float var = s2 / (float)D - mean * mean;
    const float rstd = 1.0f / sqrtf(var + LN_EPS);
#pragma unroll
    for (int k = 0; k < 4; ++k)
        out[tid + k * 1024] = (v[k] - mean) * rstd;
}

extern "C" void kernel_launch(void* const* d_in, const int* in_sizes, int n_in,
                              void* d_out, int out_size, void* d_ws, size_t ws_size,
                              hipStream_t stream) {
    const float* states     = (const float*)d_in[0];
    const float* weights    = (const float*)d_in[1];
    const float* timestamps = (const float*)d_in[2];
    const float* current    = (const float*)d_in[3];
    // d_in[4] = sensed_state: not used in the output math.
    const float* t_new      = (const float*)d_in[5];
    float* out = (float*)d_out;

    const int M = in_sizes[1];   // 8192
    const int D = in_sizes[3];   // 4096

    float* ws       = (float*)d_ws;
    float* partial  = ws;                              // [NB * D] (8 MiB)
    float* partial2 = partial + (size_t)NB * D;        // [NP2 * D]
    float* partE    = partial2 + (size_t)NP2 * D;      // [NB]
    float* partS    = partE + NB;                      // [NB]

    const float scale = 1.0f / sqrtf((float)D);

    fused_kernel<<<NB, 512, 0, stream>>>(
        states, current, weights, timestamps, t_new,
        partial, partE, partS, M, D, scale);

    {
        dim3 grid(D / 256, NP2);   // (16, 8)
        reduce_kernel<<<grid, 256, 0, stream>>>(partial, partial2, D);
    }

    finalize_kernel<<<1, 1024, 0, stream>>>(partial2, partE, partS, current, out, D);
}